// Round 4
// baseline (181.916 us; speedup 1.0000x reference)
//
#include <hip/hip_runtime.h>
#include <math.h>

#define KC 33            // clusters
#define ED 32            // embedding dim
#define KE (KC * ED)     // 1056
#define PAD 33           // padded leading dim for LDS tiles

#define BPB 64           // blocks per batch -> grid = 8*64 = 512 = 2 blocks/CU
#define TPA 128          // points per phase-1 tile
#define NT 8             // phase-1 tiles (chunk = 1024 points)
#define NSLOT 8          // half-wave private sum copies
#define NT2 4            // phase-2 double-tiles (256 points each)

// ws layout (floats): sums[B*KE] | counts[B*KC] | var[B] | done[B] | ready[B]

__global__ void k_zero(float* __restrict__ ws, int n, float* __restrict__ out) {
    int i = blockIdx.x * blockDim.x + threadIdx.x;
    if (i < n) ws[i] = 0.f;
    if (i == 0) out[0] = 0.f;
}

// Fused accum + hinge, ONE pass over HBM. Grid = 512 blocks = exactly 2/CU
// (LDS 73KB <= 80KB, __launch_bounds__(256,2)) so all blocks are co-resident
// and a software release/acquire barrier per batch is safe (cooperative launch
// is not executed under the harness's graph capture -- r3 evidence).
// Phase 1 = r2 k_accum body verbatim (bit-identical sums/counts). Software
// barrier. Centers via agent-scope atomic loads (per-XCD L2 non-coherence).
// Phase 2 = r2 k_hinge body re-reading this block's own chunk (L2/L3-hot;
// avoids holding 128 data VGPRs across phases -> no scratch-spill hazard).
// Labels stay register-resident. Last block per batch runs the epilogue.
__global__ __launch_bounds__(256, 2) void k_fused(
        const float* __restrict__ emb, const int* __restrict__ lab,
        float* __restrict__ sums, float* __restrict__ counts,
        float* __restrict__ var, unsigned* __restrict__ done,
        unsigned* __restrict__ ready, float* __restrict__ out,
        int N, int B) {
    __shared__ float s_tile[2 * TPA * PAD];  // 33.8 KB (phase 1 uses rows 0-127)
    __shared__ float s_priv[NSLOT * KE];     // 33.8 KB
    __shared__ float s_hist[2 * KC];
    __shared__ int   s_lab[2 * TPA];
    __shared__ float s_ctr[KC * PAD];        // 4.4 KB
    __shared__ float s_cnt[KC];
    __shared__ float s_inv[KC];
    __shared__ int   s_prs[KC];
    __shared__ float s_reg[KC];
    __shared__ float s_red[4];
    __shared__ float s_red2[256];
    __shared__ int   s_last;
    int t = threadIdx.x;
    int b = blockIdx.x / BPB;
    int blk = blockIdx.x % BPB;
    int chunk = N / BPB;                     // 1024
    int e = t & 31, slot = t >> 3 >> 2;      // slot = t>>5
    slot = t >> 5;
    size_t pbase = (size_t)b * N + (size_t)blk * chunk;
    const float4* g4 = (const float4*)(emb + pbase * ED);

    for (int i = t; i < NSLOT * KE; i += 256) s_priv[i] = 0.f;
    if (t < 2 * KC) s_hist[t] = 0.f;

    // labels: register-resident for both phases (8 ints on t<128)
    int rl_all[NT];
    if (t < TPA) {
#pragma unroll
        for (int tb = 0; tb < NT; tb++) rl_all[tb] = lab[pbase + tb * TPA + t];
    }

    // ---- phase 1: per-(b,k) sums + histogram (r2 k_accum body) ----
    float4 r0 = g4[t], r1 = g4[t + 256], r2 = g4[t + 512], r3 = g4[t + 768];
    __syncthreads();                          // priv + hist init done

    for (int tb = 0; tb < NT; tb++) {
        {
            int f, p, m;
            f = t;        p = f >> 3; m = (f & 7) * 4;
            { float* d = &s_tile[PAD * p + m]; d[0]=r0.x; d[1]=r0.y; d[2]=r0.z; d[3]=r0.w; }
            f = t + 256;  p = f >> 3; m = (f & 7) * 4;
            { float* d = &s_tile[PAD * p + m]; d[0]=r1.x; d[1]=r1.y; d[2]=r1.z; d[3]=r1.w; }
            f = t + 512;  p = f >> 3; m = (f & 7) * 4;
            { float* d = &s_tile[PAD * p + m]; d[0]=r2.x; d[1]=r2.y; d[2]=r2.z; d[3]=r2.w; }
            f = t + 768;  p = f >> 3; m = (f & 7) * 4;
            { float* d = &s_tile[PAD * p + m]; d[0]=r3.x; d[1]=r3.y; d[2]=r3.z; d[3]=r3.w; }
        }
        if (t < TPA) {
            s_lab[t] = rl_all[tb];
            atomicAdd(&s_hist[(t >> 6) * KC + rl_all[tb]], 1.f);
        }
        __syncthreads();

        if (tb + 1 < NT) {
            const float4* gn = (const float4*)(emb + (pbase + (size_t)(tb + 1) * TPA) * ED);
            r0 = gn[t]; r1 = gn[t + 256]; r2 = gn[t + 512]; r3 = gn[t + 768];
        }

        float* priv = &s_priv[slot * KE];
#pragma unroll
        for (int st = 0; st < TPA / NSLOT; st++) {
            int pt = st * NSLOT + slot;
            float x = s_tile[pt * PAD + e];
            int k = s_lab[pt];
            priv[k * ED + e] += x;           // private: no atomic; bank=e: free
        }
        __syncthreads();
    }
    for (int i = t; i < KE; i += 256) {
        float v = 0.f;
#pragma unroll
        for (int s = 0; s < NSLOT; s++) v += s_priv[s * KE + i];
        atomicAdd(&sums[(size_t)b * KE + i], v);
    }
    if (t < KC)
        atomicAdd(&counts[b * KC + t], s_hist[t] + s_hist[KC + t]);
    __syncthreads();                         // drains vmcnt: block's atomics performed

    // ---- software per-batch barrier (release/acquire via ready[b]) ----
    if (t == 0) {
        __threadfence();
        atomicAdd(&ready[b], 1u);
        while (__hip_atomic_load(&ready[b], __ATOMIC_ACQUIRE,
                                 __HIP_MEMORY_SCOPE_AGENT) < (unsigned)BPB)
            __builtin_amdgcn_s_sleep(8);
    }
    __syncthreads();

    // ---- centers (agent-scope loads: sums/counts written by other XCDs) ----
    if (t < KC) {
        float c = __hip_atomic_load(&counts[b * KC + t], __ATOMIC_RELAXED,
                                    __HIP_MEMORY_SCOPE_AGENT);
        s_cnt[t] = fmaxf(c, 1.f);
        int p = (t > 0 && c > 0.f) ? 1 : 0;
        s_inv[t] = p ? 1.f / fmaxf(c, 1.f) : 0.f;
        s_prs[t] = p;
    }
    __syncthreads();
    for (int i = t; i < KE; i += 256) {
        int k = i >> 5, e2 = i & 31;
        float sv = __hip_atomic_load(&sums[(size_t)b * KE + i], __ATOMIC_RELAXED,
                                     __HIP_MEMORY_SCOPE_AGENT);
        s_ctr[k * PAD + e2] = sv / s_cnt[k];
    }

    // ---- phase 2: hinge (r2 k_hinge body; this block's chunk is L2/L3-hot) ----
    float4 x0 = g4[t],        x1 = g4[t + 256],  x2 = g4[t + 512],  x3 = g4[t + 768];
    float4 x4 = g4[t + 1024], x5 = g4[t + 1280], x6 = g4[t + 1536], x7 = g4[t + 1792];

    float hs = 0.f;
    for (int i2 = 0; i2 < NT2; i2++) {
        {
            int f, p, m;
            f = t;         p = f >> 3; m = (f & 7) * 4;
            { float* d = &s_tile[PAD * p + m]; d[0]=x0.x; d[1]=x0.y; d[2]=x0.z; d[3]=x0.w; }
            f = t + 256;   p = f >> 3; m = (f & 7) * 4;
            { float* d = &s_tile[PAD * p + m]; d[0]=x1.x; d[1]=x1.y; d[2]=x1.z; d[3]=x1.w; }
            f = t + 512;   p = f >> 3; m = (f & 7) * 4;
            { float* d = &s_tile[PAD * p + m]; d[0]=x2.x; d[1]=x2.y; d[2]=x2.z; d[3]=x2.w; }
            f = t + 768;   p = f >> 3; m = (f & 7) * 4;
            { float* d = &s_tile[PAD * p + m]; d[0]=x3.x; d[1]=x3.y; d[2]=x3.z; d[3]=x3.w; }
            f = t + 1024;  p = f >> 3; m = (f & 7) * 4;
            { float* d = &s_tile[PAD * p + m]; d[0]=x4.x; d[1]=x4.y; d[2]=x4.z; d[3]=x4.w; }
            f = t + 1280;  p = f >> 3; m = (f & 7) * 4;
            { float* d = &s_tile[PAD * p + m]; d[0]=x5.x; d[1]=x5.y; d[2]=x5.z; d[3]=x5.w; }
            f = t + 1536;  p = f >> 3; m = (f & 7) * 4;
            { float* d = &s_tile[PAD * p + m]; d[0]=x6.x; d[1]=x6.y; d[2]=x6.z; d[3]=x6.w; }
            f = t + 1792;  p = f >> 3; m = (f & 7) * 4;
            { float* d = &s_tile[PAD * p + m]; d[0]=x7.x; d[1]=x7.y; d[2]=x7.z; d[3]=x7.w; }
        }
        if (t < TPA) {
            s_lab[t]       = rl_all[2 * i2];
            s_lab[t + TPA] = rl_all[2 * i2 + 1];
        }
        __syncthreads();

        if (i2 + 1 < NT2) {
            const float4* gn = g4 + (size_t)(i2 + 1) * 2048;
            x0 = gn[t];        x1 = gn[t + 256];  x2 = gn[t + 512];  x3 = gn[t + 768];
            x4 = gn[t + 1024]; x5 = gn[t + 1280]; x6 = gn[t + 1536]; x7 = gn[t + 1792];
        }

        int   k  = s_lab[t];
        float iv = s_inv[k];
        const float* xr = &s_tile[t * PAD];
        const float* cr = &s_ctr[k * PAD];
        float d2 = 0.f;
#pragma unroll
        for (int j = 0; j < ED; j++) {
            float d = xr[j] - cr[j];
            d2 = fmaf(d, d, d2);
        }
        float dist = sqrtf(fmaxf(d2, 1e-12f));
        hs += fmaxf(dist - 0.5f, 0.f) * iv;
        __syncthreads();
    }

    // block reduction of hs
    hs += __shfl_xor(hs, 1);  hs += __shfl_xor(hs, 2);  hs += __shfl_xor(hs, 4);
    hs += __shfl_xor(hs, 8);  hs += __shfl_xor(hs, 16); hs += __shfl_xor(hs, 32);
    if ((t & 63) == 0) s_red[t >> 6] = hs;
    __syncthreads();
    if (t == 0) {
        atomicAdd(&var[b], s_red[0] + s_red[1] + s_red[2] + s_red[3]);
        __threadfence();                     // release var add before done++
        unsigned old = atomicAdd(&done[b], 1u);
        s_last = (old == (unsigned)(BPB - 1)) ? 1 : 0;
    }
    __syncthreads();
    if (!s_last) return;

    // ---- epilogue (last block of this batch; centers already in LDS) ----
    __threadfence();                         // acquire other blocks' var adds
    if (t < KC) {
        float n2 = 0.f;
        for (int e2 = 0; e2 < ED; e2++) { float c = s_ctr[t * PAD + e2]; n2 += c * c; }
        s_reg[t] = s_prs[t] ? sqrtf(fmaxf(n2, 1e-12f)) : 0.f;
    }
    __syncthreads();

    float psum = 0.f;
    for (int q = t; q < KC * KC; q += 256) {
        int i = q / KC, j = q % KC;
        if (i < j && s_prs[i] && s_prs[j]) {
            float d2 = 0.f;
            for (int e2 = 0; e2 < ED; e2++) {
                float d = s_ctr[i * PAD + e2] - s_ctr[j * PAD + e2];
                d2 += d * d;
            }
            float cd = sqrtf(fmaxf(d2, 1e-12f));
            psum += fmaxf(3.0f - cd, 0.f);   // 2*DELTA_D = 3.0
        }
    }
    s_red2[t] = psum;
    __syncthreads();
    for (int s = 128; s > 0; s >>= 1) {
        if (t < s) s_red2[t] += s_red2[t + s];
        __syncthreads();
    }

    if (t == 0) {
        float vb = atomicAdd(&var[b], 0.f);  // device-coherent read
        float reg = 0.f; int n = 0;
        for (int k = 0; k < KC; k++) { reg += s_reg[k]; n += s_prs[k]; }
        float nf = (float)n;
        float variance_term = vb / fmaxf(nf, 1.f);
        float npairs = nf * (nf - 1.f) * 0.5f;
        float distance_term = s_red2[0] / fmaxf(npairs, 1.f);
        float reg_term = reg / fmaxf(nf, 1.f);
        float pb = variance_term + distance_term + 0.001f * reg_term;
        if (n == 0) pb = 0.f;
        atomicAdd(out, pb / (float)B);
    }
}

extern "C" void kernel_launch(void* const* d_in, const int* in_sizes, int n_in,
                              void* d_out, int out_size, void* d_ws, size_t ws_size,
                              hipStream_t stream) {
    const float* emb = (const float*)d_in[0];
    const int*   lab = (const int*)d_in[1];
    float* out = (float*)d_out;

    int B = 8;
    int N = in_sizes[1] / B;                 // 65536

    float*    sums   = (float*)d_ws;
    float*    counts = sums + (size_t)B * KE;
    float*    var    = counts + (size_t)B * KC;
    unsigned* done   = (unsigned*)(var + B);
    unsigned* ready  = done + B;

    int zn = B * KE + B * KC + B + B + B;
    k_zero<<<(zn + 255) / 256, 256, 0, stream>>>((float*)d_ws, zn, out);
    k_fused<<<B * BPB, 256, 0, stream>>>(emb, lab, sums, counts, var, done,
                                         ready, out, N, B);
}

// Round 6
// 131.041 us; speedup vs baseline: 1.3882x; 1.3882x over previous
//
#include <hip/hip_runtime.h>
#include <math.h>

#define KC 33            // clusters
#define ED 32            // embedding dim
#define KE (KC * ED)     // 1056
#define PAD 33           // padded leading dim for LDS tiles

// accum geometry
#define BPB_A 64         // blocks per batch
#define TPA 128          // points per staged tile
#define NSLOT 8          // half-waves per 256-thread block
// hinge geometry
#define BPB_H 128
#define TPH 256          // points per staged tile (1 per thread)

// ws layout (floats): sums[B*KE] | counts[B*KC] | var[B]

__global__ void k_zero(float* __restrict__ ws, int n, float* __restrict__ out) {
    int i = blockIdx.x * blockDim.x + threadIdx.x;
    if (i < n) ws[i] = 0.f;
    if (i == 0) out[0] = 0.f;
}

// Pass 1: per-(b,k) embedding sums + fused label histogram (replaces the
// separate k_hist pass: labels are already staged here). Register-prefetch
// pipelined staging into a +33-padded LDS tile; half-wave per point (lane=dim)
// non-atomic RMW into per-half-wave private copies (bank = e both halves: free).
__global__ __launch_bounds__(256) void k_accum(const float* __restrict__ emb,
                                               const int* __restrict__ lab,
                                               float* __restrict__ sums,
                                               float* __restrict__ counts, int N) {
    __shared__ float s_tile[TPA * PAD];      // 16.9 KB
    __shared__ float s_priv[NSLOT * KE];     // 33 KB
    __shared__ int   s_lab[TPA];
    __shared__ float s_hist[2 * KC];
    int t = threadIdx.x;
    for (int i = t; i < NSLOT * KE; i += 256) s_priv[i] = 0.f;
    if (t < 2 * KC) s_hist[t] = 0.f;

    int b     = blockIdx.x / BPB_A;
    int blk   = blockIdx.x % BPB_A;
    int chunk = N / BPB_A;                   // 1024
    int e     = t & 31;
    int slot  = t >> 5;
    size_t pbase = (size_t)b * N + (size_t)blk * chunk;
    const int NT = chunk / TPA;              // 8 tiles

    // prefetch tile 0
    const float4* g4 = (const float4*)(emb + pbase * ED);
    float4 r0 = g4[t], r1 = g4[t + 256], r2 = g4[t + 512], r3 = g4[t + 768];
    int rl = 0;
    if (t < TPA) rl = lab[pbase + t];
    __syncthreads();                          // priv + hist init done

    for (int tb = 0; tb < NT; tb++) {
        // unpack staged registers into padded tile
        {
            int f, p, m;
            f = t;        p = f >> 3; m = (f & 7) * 4;
            { float* d = &s_tile[PAD * p + m]; d[0]=r0.x; d[1]=r0.y; d[2]=r0.z; d[3]=r0.w; }
            f = t + 256;  p = f >> 3; m = (f & 7) * 4;
            { float* d = &s_tile[PAD * p + m]; d[0]=r1.x; d[1]=r1.y; d[2]=r1.z; d[3]=r1.w; }
            f = t + 512;  p = f >> 3; m = (f & 7) * 4;
            { float* d = &s_tile[PAD * p + m]; d[0]=r2.x; d[1]=r2.y; d[2]=r2.z; d[3]=r2.w; }
            f = t + 768;  p = f >> 3; m = (f & 7) * 4;
            { float* d = &s_tile[PAD * p + m]; d[0]=r3.x; d[1]=r3.y; d[2]=r3.z; d[3]=r3.w; }
        }
        if (t < TPA) {
            s_lab[t] = rl;
            atomicAdd(&s_hist[(t >> 6) * KC + rl], 1.f);   // fused histogram
        }
        __syncthreads();

        // prefetch next tile while computing this one
        if (tb + 1 < NT) {
            const float4* gn = (const float4*)(emb + (pbase + (size_t)(tb + 1) * TPA) * ED);
            r0 = gn[t]; r1 = gn[t + 256]; r2 = gn[t + 512]; r3 = gn[t + 768];
            if (t < TPA) rl = lab[pbase + (size_t)(tb + 1) * TPA + t];
        }

        float* priv = &s_priv[slot * KE];
#pragma unroll
        for (int st = 0; st < TPA / NSLOT; st++) {
            int pt = st * NSLOT + slot;
            float x = s_tile[pt * PAD + e];
            int   k = s_lab[pt];
            priv[k * ED + e] += x;           // private: no atomic; bank=e: free
        }
        __syncthreads();
    }

    for (int i = t; i < KE; i += 256) {
        float v = 0.f;
#pragma unroll
        for (int s = 0; s < NSLOT; s++) v += s_priv[s * KE + i];
        atomicAdd(&sums[(size_t)b * KE + i], v);
    }
    if (t < KC)
        atomicAdd(&counts[b * KC + t], s_hist[t] + s_hist[KC + t]);
}

// Pass 2: lane-owns-point hinge (r0 body verbatim -- the fused
// done-counter/threadfence/epilogue variant measured +10us on this kernel, so
// the epilogue stays in a separate k_final). Each block recomputes its batch's
// centers from sums/counts. var[b] += sum_p max(||x-c||-0.5,0)*inv[k_p].
__global__ __launch_bounds__(256) void k_hinge(const float* __restrict__ emb,
                                               const int* __restrict__ lab,
                                               const float* __restrict__ sums,
                                               const float* __restrict__ counts,
                                               float* __restrict__ var, int N) {
    __shared__ float s_tile[TPH * PAD];      // 33.8 KB
    __shared__ float s_ctr[KC * PAD];        // 4.3 KB, padded
    __shared__ float s_cnt[KC];
    __shared__ float s_inv[KC];
    __shared__ int   s_lab[TPH];
    __shared__ float s_red[4];
    int t     = threadIdx.x;
    int b     = blockIdx.x / BPB_H;
    int blk   = blockIdx.x % BPB_H;
    int chunk = N / BPB_H;                   // 512
    size_t pbase = (size_t)b * N + (size_t)blk * chunk;
    const int NT = chunk / TPH;              // 2 tiles

    // prefetch tile 0 (8 float4 per thread = 1 point per thread)
    const float4* g4 = (const float4*)(emb + pbase * ED);
    float4 r0 = g4[t],        r1 = g4[t + 256],  r2 = g4[t + 512],  r3 = g4[t + 768];
    float4 r4 = g4[t + 1024], r5 = g4[t + 1280], r6 = g4[t + 1536], r7 = g4[t + 1792];
    int rl = lab[pbase + t];

    if (t < KC) {
        float c = counts[b * KC + t];
        s_cnt[t] = fmaxf(c, 1.f);
        s_inv[t] = (t > 0 && c > 0.f) ? 1.f / fmaxf(c, 1.f) : 0.f;
    }
    __syncthreads();
    for (int i = t; i < KE; i += 256) {
        int k = i >> 5, e = i & 31;
        s_ctr[k * PAD + e] = sums[(size_t)b * KE + i] / s_cnt[k];
    }

    float hs = 0.f;
    for (int tb = 0; tb < NT; tb++) {
        {
            int f, p, m;
            f = t;         p = f >> 3; m = (f & 7) * 4;
            { float* d = &s_tile[PAD * p + m]; d[0]=r0.x; d[1]=r0.y; d[2]=r0.z; d[3]=r0.w; }
            f = t + 256;   p = f >> 3; m = (f & 7) * 4;
            { float* d = &s_tile[PAD * p + m]; d[0]=r1.x; d[1]=r1.y; d[2]=r1.z; d[3]=r1.w; }
            f = t + 512;   p = f >> 3; m = (f & 7) * 4;
            { float* d = &s_tile[PAD * p + m]; d[0]=r2.x; d[1]=r2.y; d[2]=r2.z; d[3]=r2.w; }
            f = t + 768;   p = f >> 3; m = (f & 7) * 4;
            { float* d = &s_tile[PAD * p + m]; d[0]=r3.x; d[1]=r3.y; d[2]=r3.z; d[3]=r3.w; }
            f = t + 1024;  p = f >> 3; m = (f & 7) * 4;
            { float* d = &s_tile[PAD * p + m]; d[0]=r4.x; d[1]=r4.y; d[2]=r4.z; d[3]=r4.w; }
            f = t + 1280;  p = f >> 3; m = (f & 7) * 4;
            { float* d = &s_tile[PAD * p + m]; d[0]=r5.x; d[1]=r5.y; d[2]=r5.z; d[3]=r5.w; }
            f = t + 1536;  p = f >> 3; m = (f & 7) * 4;
            { float* d = &s_tile[PAD * p + m]; d[0]=r6.x; d[1]=r6.y; d[2]=r6.z; d[3]=r6.w; }
            f = t + 1792;  p = f >> 3; m = (f & 7) * 4;
            { float* d = &s_tile[PAD * p + m]; d[0]=r7.x; d[1]=r7.y; d[2]=r7.z; d[3]=r7.w; }
        }
        s_lab[t] = rl;
        __syncthreads();

        if (tb + 1 < NT) {
            const float4* gn = (const float4*)(emb + (pbase + (size_t)(tb + 1) * TPH) * ED);
            r0 = gn[t];        r1 = gn[t + 256];  r2 = gn[t + 512];  r3 = gn[t + 768];
            r4 = gn[t + 1024]; r5 = gn[t + 1280]; r6 = gn[t + 1536]; r7 = gn[t + 1792];
            rl = lab[pbase + (size_t)(tb + 1) * TPH + t];
        }

        int   k  = s_lab[t];
        float iv = s_inv[k];
        const float* xr = &s_tile[t * PAD];
        const float* cr = &s_ctr[k * PAD];
        float d2 = 0.f;
#pragma unroll
        for (int j = 0; j < ED; j++) {
            float d = xr[j] - cr[j];
            d2 = fmaf(d, d, d2);
        }
        float dist = sqrtf(fmaxf(d2, 1e-12f));
        hs += fmaxf(dist - 0.5f, 0.f) * iv;
        __syncthreads();
    }

    // block reduction of hs (one value per thread)
    hs += __shfl_xor(hs, 1);  hs += __shfl_xor(hs, 2);  hs += __shfl_xor(hs, 4);
    hs += __shfl_xor(hs, 8);  hs += __shfl_xor(hs, 16); hs += __shfl_xor(hs, 32);
    if ((t & 63) == 0) s_red[t >> 6] = hs;
    __syncthreads();
    if (t == 0)
        atomicAdd(&var[b], s_red[0] + s_red[1] + s_red[2] + s_red[3]);
}

// Epilogue: one block per batch; recompute centers from sums/counts.
__global__ __launch_bounds__(256) void k_final(const float* __restrict__ sums,
                                               const float* __restrict__ counts,
                                               const float* __restrict__ var,
                                               float* __restrict__ out, int B) {
    __shared__ float s_ctr[KE];
    __shared__ float s_cnt[KC];
    __shared__ float s_reg[KC];
    __shared__ int   s_prs[KC];
    __shared__ float s_red[256];
    int b = blockIdx.x;
    int t = threadIdx.x;

    if (t < KC) {
        float c = counts[b * KC + t];
        s_cnt[t] = fmaxf(c, 1.f);
        s_prs[t] = (t > 0 && c > 0.f) ? 1 : 0;
    }
    __syncthreads();
    for (int i = t; i < KE; i += 256)
        s_ctr[i] = sums[(size_t)b * KE + i] / s_cnt[i >> 5];
    __syncthreads();
    if (t < KC) {
        float n2 = 0.f;
        for (int e2 = 0; e2 < ED; e2++) { float c = s_ctr[t * ED + e2]; n2 += c * c; }
        s_reg[t] = s_prs[t] ? sqrtf(fmaxf(n2, 1e-12f)) : 0.f;
    }
    __syncthreads();

    float psum = 0.f;
    for (int q = t; q < KC * KC; q += 256) {
        int i = q / KC, j = q % KC;
        if (i < j && s_prs[i] && s_prs[j]) {
            float d2 = 0.f;
            for (int e2 = 0; e2 < ED; e2++) {
                float d = s_ctr[i * ED + e2] - s_ctr[j * ED + e2];
                d2 += d * d;
            }
            float cd = sqrtf(fmaxf(d2, 1e-12f));
            psum += fmaxf(3.0f - cd, 0.f);   // 2*DELTA_D = 3.0
        }
    }
    s_red[t] = psum;
    __syncthreads();
    for (int s = 128; s > 0; s >>= 1) {
        if (t < s) s_red[t] += s_red[t + s];
        __syncthreads();
    }

    if (t == 0) {
        float reg = 0.f; int n = 0;
        for (int k = 0; k < KC; k++) { reg += s_reg[k]; n += s_prs[k]; }
        float nf = (float)n;
        float variance_term = var[b] / fmaxf(nf, 1.f);
        float npairs = nf * (nf - 1.f) * 0.5f;
        float distance_term = s_red[0] / fmaxf(npairs, 1.f);
        float reg_term = reg / fmaxf(nf, 1.f);
        float pb = variance_term + distance_term + 0.001f * reg_term;
        if (n == 0) pb = 0.f;
        atomicAdd(out, pb / (float)B);
    }
}

extern "C" void kernel_launch(void* const* d_in, const int* in_sizes, int n_in,
                              void* d_out, int out_size, void* d_ws, size_t ws_size,
                              hipStream_t stream) {
    const float* emb = (const float*)d_in[0];
    const int*   lab = (const int*)d_in[1];
    float* out = (float*)d_out;

    const int B = 8;
    const int N = in_sizes[1] / B;   // 65536

    float* sums   = (float*)d_ws;
    float* counts = sums + (size_t)B * KE;
    float* var    = counts + (size_t)B * KC;

    int zn = B * KE + B * KC + B;
    k_zero<<<(zn + 255) / 256, 256, 0, stream>>>(sums, zn, out);
    k_accum<<<B * BPB_A, 256, 0, stream>>>(emb, lab, sums, counts, N);
    k_hinge<<<B * BPB_H, 256, 0, stream>>>(emb, lab, sums, counts, var, N);
    k_final<<<B, 256, 0, stream>>>(sums, counts, var, out, B);
}